// Round 8
// baseline (1661.022 us; speedup 1.0000x reference)
//
#include <hip/hip_runtime.h>
#include <hip/hip_bf16.h>

// MoE FFN, top-1 switch routing. fp32 end-to-end (no fp32 MFMA on CDNA4).
// Sparse dispatch via device-built WORK-LIST: one entry per alive
// (expert, row-block); GEMM grids are 1280 compact blocks (<=39 alive
// m-slots + col/split dims). Bijective XCD-chunk swizzle clusters all
// row-blocks of a col-panel on one XCD (panel set = 8 experts x 0.5MB
// = 4MB = one XCD L2) for weight reuse. LDS double-buffered, ONE
// barrier per k-iter.
//
// R7 evidence: VALUBusy 45%, Occ 10.3%, FETCH 549MB (=4x W1) -> fixes:
// work-list (dead-block churn + even spread), XCD chunking (L2 reuse),
// dbuf (halve barrier stalls).
//
// GEMM2 (N=1024) split-K=4; s=0 partial -> d_out, s>0 -> ws; reduce
// kernel applies sum + bias + route_p.

#define D_MODEL 1024
#define MLP_DIM 4096
#define N_EXPERTS 8
#define N_TOK 4096
#define KSPLIT 4
#define WLMAX 40   // max alive (e,row-block) entries: <=39 (+1 pad)
#define NWG 1280   // 32 * WLMAX  (also = 8 * 4 * WLMAX for split GEMM2)
#define CHUNK (NWG / 8)

// ---------------- router: logits -> softmax max prob + argmax ----------------
__global__ __launch_bounds__(64) void router_kernel(
    const float* __restrict__ x, const float* __restrict__ w_gate,
    const float* __restrict__ b_gate, int* __restrict__ route_idx,
    float* __restrict__ route_p) {
  int t = blockIdx.x;
  int lane = threadIdx.x;
  const float* xr = x + (size_t)t * D_MODEL;
  float acc[N_EXPERTS];
#pragma unroll
  for (int e = 0; e < N_EXPERTS; ++e) acc[e] = 0.f;
#pragma unroll
  for (int i = 0; i < D_MODEL / 64; ++i) {
    int idx = i * 64 + lane;
    float xv = xr[idx];
    const float* wg = w_gate + (size_t)idx * N_EXPERTS;
#pragma unroll
    for (int e = 0; e < N_EXPERTS; ++e) acc[e] += xv * wg[e];
  }
#pragma unroll
  for (int off = 32; off >= 1; off >>= 1) {
#pragma unroll
    for (int e = 0; e < N_EXPERTS; ++e) acc[e] += __shfl_xor(acc[e], off, 64);
  }
  if (lane == 0) {
    float l[N_EXPERTS];
#pragma unroll
    for (int e = 0; e < N_EXPERTS; ++e) l[e] = acc[e] + b_gate[e];
    // strict > : first-max tiebreak, matches jnp.argmax (softmax monotonic)
    float m = l[0];
    int bi = 0;
#pragma unroll
    for (int e = 1; e < N_EXPERTS; ++e) {
      if (l[e] > m) { m = l[e]; bi = e; }
    }
    float s = 0.f;
#pragma unroll
    for (int e = 0; e < N_EXPERTS; ++e) s += expf(l[e] - m);
    route_idx[t] = bi;
    route_p[t] = 1.0f / s;  // max softmax prob = exp(0)/sum
  }
}

// ---------------- bucketize tokens per expert ----------------
__global__ void bucket_kernel(const int* __restrict__ route_idx,
                              int* __restrict__ counts,
                              int* __restrict__ bucket) {
  int t = blockIdx.x * blockDim.x + threadIdx.x;
  if (t < N_TOK) {
    int e = route_idx[t];
    int pos = atomicAdd(&counts[e], 1);
    bucket[e * N_TOK + pos] = t;
  }
}

// ---------------- work-list: alive (expert,row0) pairs ----------------
__global__ void worklist_kernel(const int* __restrict__ counts,
                                int* __restrict__ mlist_e,
                                int* __restrict__ mlist_r,
                                int* __restrict__ Mp) {
  if (threadIdx.x == 0) {
    int m = 0;
    for (int e = 0; e < N_EXPERTS; ++e) {
      int c = counts[e];
      for (int r = 0; r < c; r += 128) {
        mlist_e[m] = e;
        mlist_r[m] = r;
        ++m;
      }
    }
    *Mp = m;  // <= 39
  }
}

// ---------------- gathered expert GEMM (work-list driven) ----------------
// 128x128 tile, BK=16, 256 threads, 8x8 micro-tile as 2x2 blocks of 4x4.
// Double-buffered LDS, one barrier per k-iter:
//   iter t: load regs(t+1) | compute buf[t&1] | write buf[(t+1)&1] | barrier
// (write at t targets the buffer last READ at t-1; barrier_{t-1} separates.)
// Work decode from XCD-chunk-swizzled linear id:
//   w = (L%8)*CHUNK + L/8  -> XCD x processes contiguous w-chunk
//   GEMM1: col = w/WLMAX (32), m = w%WLMAX
//   GEMM2: m = w%WLMAX, cs = w/WLMAX, col = cs&7, s = cs>>3
template <bool SPLIT>
__global__ __launch_bounds__(256) void expert_gemm(
    const float* __restrict__ A, const float* __restrict__ B,
    const float* __restrict__ bias, float* __restrict__ C0,
    float* __restrict__ partials, const int* __restrict__ bucket,
    const int* __restrict__ counts, const int* __restrict__ mlist_e,
    const int* __restrict__ mlist_r, const int* __restrict__ Mp,
    int Kstride, int Ncols) {
  constexpr int BM = 128, BN = 128, BK = 16;
  constexpr int LDA = BM + 4, LDB = BN + 4;  // break pow2 strides
  const int L = blockIdx.x;
  const int w = (L & 7) * CHUNK + (L >> 3);  // bijective XCD chunking
  int m, colblk, kbeg, kend;
  float* Cp;
  if (SPLIT) {
    m = w % WLMAX;
    int cs = w / WLMAX;       // 0..31
    colblk = cs & 7;
    int s = cs >> 3;          // 0..3
    kbeg = s * (MLP_DIM / KSPLIT);
    kend = kbeg + (MLP_DIM / KSPLIT);
    Cp = (s == 0) ? C0 : partials + (size_t)(s - 1) * N_TOK * D_MODEL;
  } else {
    m = w % WLMAX;
    colblk = w / WLMAX;       // 0..31
    kbeg = 0;
    kend = Kstride;
    Cp = C0;
  }
  if (m >= *Mp) return;
  const int e = mlist_e[m];
  const int row0 = mlist_r[m];
  const int cnt = counts[e];
  const int col0 = colblk * BN;

  __shared__ float As[2][BK][LDA];  // k-major (transposed store)
  __shared__ float Bs[2][BK][LDB];
  __shared__ int tokS[BM];

  const int tid = threadIdx.x;
  if (tid < BM) {
    int r = row0 + tid;
    tokS[tid] = (r < cnt) ? bucket[e * N_TOK + r] : -1;
  }
  __syncthreads();

  // A-load map: rows {ar, ar+64}, k-chunk ak (4 floats)
  const int ar = tid >> 2;
  const int ak = (tid & 3) * 4;
  // B-load map: k-row bk, col-chunk bj (8 floats = 2 float4)
  const int bk = tid >> 4;
  const int bj = (tid & 15) * 8;

  const int tx = tid & 15;  // cols tx*4 and tx*4+64
  const int ty = tid >> 4;  // rows ty*4 and ty*4+64

  float acc[2][2][4][4];
#pragma unroll
  for (int hm = 0; hm < 2; ++hm)
#pragma unroll
    for (int hn = 0; hn < 2; ++hn)
#pragma unroll
      for (int i = 0; i < 4; ++i)
#pragma unroll
        for (int j = 0; j < 4; ++j) acc[hm][hn][i][j] = 0.f;

  const int tok0 = tokS[ar], tok1 = tokS[ar + 64];
  const float* __restrict__ Ap0 =
      (tok0 >= 0) ? A + (size_t)tok0 * Kstride + ak : nullptr;
  const float* __restrict__ Ap1 =
      (tok1 >= 0) ? A + (size_t)tok1 * Kstride + ak : nullptr;
  const float* __restrict__ Bp =
      B + (size_t)e * Kstride * Ncols + (size_t)bk * Ncols + col0 + bj;

  float4 a0, a1, b0, b1;

#define LOADTILE(K0)                                          \
  a0 = make_float4(0.f, 0.f, 0.f, 0.f);                       \
  a1 = a0;                                                    \
  if (Ap0) a0 = *(const float4*)(Ap0 + (K0));                 \
  if (Ap1) a1 = *(const float4*)(Ap1 + (K0));                 \
  {                                                           \
    const float* bp = Bp + (size_t)(K0) * Ncols;              \
    b0 = *(const float4*)bp;                                  \
    b1 = *(const float4*)(bp + 4);                            \
  }

#define WRITETILE(BUF)                                        \
  As[BUF][ak + 0][ar] = a0.x;                                 \
  As[BUF][ak + 1][ar] = a0.y;                                 \
  As[BUF][ak + 2][ar] = a0.z;                                 \
  As[BUF][ak + 3][ar] = a0.w;                                 \
  As[BUF][ak + 0][ar + 64] = a1.x;                            \
  As[BUF][ak + 1][ar + 64] = a1.y;                            \
  As[BUF][ak + 2][ar + 64] = a1.z;                            \
  As[BUF][ak + 3][ar + 64] = a1.w;                            \
  *(float4*)&Bs[BUF][bk][bj] = b0;                            \
  *(float4*)&Bs[BUF][bk][bj + 4] = b1;

  // prologue: stage tile 0 into buffer 0
  LOADTILE(kbeg);
  WRITETILE(0);
  __syncthreads();

  const int nt = (kend - kbeg) / BK;
  for (int t = 0; t < nt; ++t) {
    const int cur = t & 1;
    const bool more = (t + 1 < nt);
    if (more) {
      const int kn = kbeg + (t + 1) * BK;
      LOADTILE(kn);  // global loads issued; latency hidden under compute
    }

#pragma unroll
    for (int kk = 0; kk < BK; ++kk) {
      float av[2][4], bv[2][4];
      *(float4*)&av[0][0] = *(const float4*)&As[cur][kk][ty * 4];
      *(float4*)&av[1][0] = *(const float4*)&As[cur][kk][ty * 4 + 64];
      *(float4*)&bv[0][0] = *(const float4*)&Bs[cur][kk][tx * 4];
      *(float4*)&bv[1][0] = *(const float4*)&Bs[cur][kk][tx * 4 + 64];
#pragma unroll
      for (int hm = 0; hm < 2; ++hm)
#pragma unroll
        for (int hn = 0; hn < 2; ++hn)
#pragma unroll
          for (int i = 0; i < 4; ++i)
#pragma unroll
            for (int j = 0; j < 4; ++j)
              acc[hm][hn][i][j] += av[hm][i] * bv[hn][j];
    }

    if (more) {
      WRITETILE(cur ^ 1);   // buffer last read at iter t-1 (barrier-separated)
      __syncthreads();
    }
  }

#undef LOADTILE
#undef WRITETILE

  if (SPLIT) {
    // raw k-slice partial, no bias/epilogue
#pragma unroll
    for (int hm = 0; hm < 2; ++hm) {
#pragma unroll
      for (int i = 0; i < 4; ++i) {
        int r = hm * 64 + ty * 4 + i;
        if (row0 + r < cnt) {
          int tok = tokS[r];
#pragma unroll
          for (int hn = 0; hn < 2; ++hn) {
            float4 o;
            o.x = acc[hm][hn][i][0];
            o.y = acc[hm][hn][i][1];
            o.z = acc[hm][hn][i][2];
            o.w = acc[hm][hn][i][3];
            *(float4*)(Cp + (size_t)tok * Ncols + col0 + hn * 64 + tx * 4) = o;
          }
        }
      }
    }
  } else {
    float4 bvv[2];
    bvv[0] = *(const float4*)(bias + (size_t)e * Ncols + col0 + tx * 4);
    bvv[1] = *(const float4*)(bias + (size_t)e * Ncols + col0 + tx * 4 + 64);
#pragma unroll
    for (int hm = 0; hm < 2; ++hm) {
#pragma unroll
      for (int i = 0; i < 4; ++i) {
        int r = hm * 64 + ty * 4 + i;
        if (row0 + r < cnt) {
          int tok = tokS[r];
#pragma unroll
          for (int hn = 0; hn < 2; ++hn) {
            const float* bb = (const float*)&bvv[hn];
            float4 o;
            o.x = fmaxf(acc[hm][hn][i][0] + bb[0], 0.f);
            o.y = fmaxf(acc[hm][hn][i][1] + bb[1], 0.f);
            o.z = fmaxf(acc[hm][hn][i][2] + bb[2], 0.f);
            o.w = fmaxf(acc[hm][hn][i][3] + bb[3], 0.f);
            *(float4*)(Cp + (size_t)tok * Ncols + col0 + hn * 64 + tx * 4) = o;
          }
        }
      }
    }
  }
}

// ---------------- split-K reduce + bias + route_p epilogue ----------------
// one block per token, 256 threads = 256 float4 covering D_MODEL=1024 cols.
__global__ __launch_bounds__(256) void moe_reduce_kernel(
    float* __restrict__ out, const float* __restrict__ partials,
    const float* __restrict__ b2, const int* __restrict__ route_idx,
    const float* __restrict__ route_p) {
  int tok = blockIdx.x;
  int c = threadIdx.x * 4;
  int e = route_idx[tok];
  float p = route_p[tok];
  size_t off = (size_t)tok * D_MODEL + c;
  float4 s = *(const float4*)(out + off);
  const size_t stride = (size_t)N_TOK * D_MODEL;
#pragma unroll
  for (int sp = 0; sp < KSPLIT - 1; ++sp) {
    float4 v = *(const float4*)(partials + sp * stride + off);
    s.x += v.x; s.y += v.y; s.z += v.z; s.w += v.w;
  }
  float4 bv = *(const float4*)(b2 + (size_t)e * D_MODEL + c);
  s.x = (s.x + bv.x) * p;
  s.y = (s.y + bv.y) * p;
  s.z = (s.z + bv.z) * p;
  s.w = (s.w + bv.w) * p;
  *(float4*)(out + off) = s;
}

extern "C" void kernel_launch(void* const* d_in, const int* in_sizes, int n_in,
                              void* d_out, int out_size, void* d_ws,
                              size_t ws_size, hipStream_t stream) {
  const float* x = (const float*)d_in[0];
  const float* w_gate = (const float*)d_in[1];
  const float* b_gate = (const float*)d_in[2];
  const float* W1 = (const float*)d_in[3];
  const float* b1 = (const float*)d_in[4];
  const float* W2 = (const float*)d_in[5];
  const float* b2 = (const float*)d_in[6];
  float* out = (float*)d_out;

  // workspace layout (~112.2 MiB)
  char* ws = (char*)d_ws;
  int* route_idx = (int*)ws;                         // 16 KiB
  float* route_p = (float*)(ws + 16384);             // 16 KiB
  int* counts = (int*)(ws + 32768);                  // 32 B
  int* Mp = (int*)(ws + 32896);                      // 4 B
  int* mlist_e = (int*)(ws + 33024);                 // 160 B
  int* mlist_r = (int*)(ws + 33280);                 // 160 B
  int* bucket = (int*)(ws + 33536);                  // 128 KiB
  float* H = (float*)(ws + 165888);                  // 64 MiB
  float* partials = (float*)(ws + 165888 + (size_t)67108864);  // 48 MiB

  hipMemsetAsync(counts, 0, N_EXPERTS * sizeof(int), stream);
  router_kernel<<<N_TOK, 64, 0, stream>>>(x, w_gate, b_gate, route_idx, route_p);
  bucket_kernel<<<N_TOK / 256, 256, 0, stream>>>(route_idx, counts, bucket);
  worklist_kernel<<<1, 64, 0, stream>>>(counts, mlist_e, mlist_r, Mp);
  // layer 1: H = relu(Xg @ W1 + b1); 1280 compact blocks
  expert_gemm<false><<<NWG, 256, 0, stream>>>(x, W1, b1, H, nullptr, bucket,
                                              counts, mlist_e, mlist_r, Mp,
                                              D_MODEL, MLP_DIM);
  // layer 2 pass A: split-K=4 raw partials (s=0 -> out, s>0 -> ws)
  expert_gemm<true><<<NWG, 256, 0, stream>>>(H, W2, nullptr, out, partials,
                                             bucket, counts, mlist_e, mlist_r,
                                             Mp, MLP_DIM, D_MODEL);
  // layer 2 pass B: sum partials + bias + route_p scale
  moe_reduce_kernel<<<N_TOK, 256, 0, stream>>>(out, partials, b2, route_idx,
                                               route_p);
}